// Round 7
// baseline (94.817 us; speedup 1.0000x reference)
//
#include <hip/hip_runtime.h>
#include <hip/hip_bf16.h>
#include <stdint.h>

#define K_DIM 128
#define N_X   8192      // columns of x (the "n" / M dimension)
#define N_WO  8192      // 64*128 flattened (w,o) -> GEMM N dimension
#define OUT_TOTAL (8192UL * 64UL * 128UL)
#define CHUNKS_PER_PANEL 131072   // (8192/16 tiles) * 4 ksteps * 64 lanes

typedef __attribute__((ext_vector_type(8))) short short8;   // 8 bf16 = 4 VGPR
typedef __attribute__((ext_vector_type(4))) float f32x4;

__device__ inline unsigned short f2bf(float f) {
    union { float f; unsigned u; } v; v.f = f;
    unsigned u = v.u;
    u += 0x7fffu + ((u >> 16) & 1u);   // round-to-nearest-even
    return (unsigned short)(u >> 16);
}

// Transpose+convert BOTH panels P[128][8192] f32 (k-major, inner contiguous)
// into MFMA fragment-linear bf16 blocks. Chunk cc = ((t*4 + ks)*64 + l):
//   elem j (0..7): P[ks*32 + (l>>4)*8 + j][t*16 + (l&15)]
__global__ __launch_bounds__(256) void prep_frag2(const float* __restrict__ X,
                                                  const float* __restrict__ W,
                                                  uint4* __restrict__ Q) {
    int c  = blockIdx.x * 256 + threadIdx.x;   // 0 .. 262143
    int cc = c & (CHUNKS_PER_PANEL - 1);
    const float* P = (c >= CHUNKS_PER_PANEL) ? W : X;
    int l  = cc & 63;
    int ks = (cc >> 6) & 3;
    int t  = cc >> 8;
    int m  = t * 16 + (l & 15);
    int k0 = ks * 32 + ((l >> 4) << 3);
    const float* p = P + (size_t)k0 * N_X + m;
    unsigned short h[8];
#pragma unroll
    for (int j = 0; j < 8; ++j) h[j] = f2bf(p[(size_t)j * N_X]);
    uint4 q;
    q.x = (unsigned)h[0] | ((unsigned)h[1] << 16);
    q.y = (unsigned)h[2] | ((unsigned)h[3] << 16);
    q.z = (unsigned)h[4] | ((unsigned)h[5] << 16);
    q.w = (unsigned)h[6] | ((unsigned)h[7] << 16);
    Q[c] = q;
}

// Row-slab sweep GEMM with LDS-transposed epilogue.
// Block = 32 output rows (n) x ALL 8192 wo, 8 waves: wave (wh,wq) owns
// 16 n (wh half) x 256 wo (wq quarter) per iteration, 8 iterations.
// MFMA is operand-swapped (D[wo][n]); the per-wave PRIVATE 16 KiB LDS region
// transposes each iteration's 16x256 f32 sub-tile so every global store is a
// FULL 1 KiB contiguous wave-store (identical shape to the 7 TB/s fill).
// No barriers (same-wave lgkmcnt only, compiler-inserted).
// Swizzle: logical byte q of row r stored at physical q ^ ((r&7)<<4).
// Involution: physical p holds logical p ^ ((r&7)<<4).
__global__ __launch_bounds__(512, 2) void gemm_sweep2(const short8* __restrict__ A,
                                                      const short8* __restrict__ B,
                                                      const float* __restrict__ bias,
                                                      float* __restrict__ out) {
    extern __shared__ char lds_raw[];          // 128 KiB, 16 KiB per wave
    int bid = blockIdx.x;
    // bijective XCD swizzle (256 % 8 == 0): 32 consecutive slabs per XCD
    int swz = (bid & 7) * 32 + (bid >> 3);
    int n0  = swz * 32;

    int tid  = threadIdx.x;
    int lane = tid & 63;
    int w    = tid >> 6;               // 0..7
    int wh = w >> 2, wq = w & 3;       // n-half, wo-quarter
    int cl = lane & 15, rg = (lane >> 4) << 2;

    char* ldsw = lds_raw + w * 16384;  // private region

    // x fragments for this wave's 16-row tile, all 4 K-steps (VGPR-resident)
    int tA = swz * 2 + wh;
    short8 xf[4];
#pragma unroll
    for (int ks = 0; ks < 4; ++ks)
        xf[ks] = A[(size_t)(tA * 4 + ks) * 64 + lane];

    // bias for the epilogue: lane stores logical floats 4*lane..4*lane+3 of a
    // 256-wide span whose base is a multiple of 128 -> idx = 4*(lane&31).
    f32x4 bv = *(const f32x4*)(bias + ((lane & 31) << 2));
    bv.x *= 128.0f; bv.y *= 128.0f; bv.z *= 128.0f; bv.w *= 128.0f;

    for (int it = 0; it < 8; ++it) {
        int t0 = it * 64 + wq * 16;    // this wave's first wo-tile
        f32x4 acc[16] = {};
#pragma unroll
        for (int ks = 0; ks < 4; ++ks) {
            short8 wf[16];
#pragma unroll
            for (int j = 0; j < 16; ++j)
                wf[j] = B[(size_t)((t0 + j) * 4 + ks) * 64 + lane];
#pragma unroll
            for (int j = 0; j < 16; ++j)
                acc[j] = __builtin_amdgcn_mfma_f32_16x16x32_bf16(
                    wf[j], xf[ks], acc[j], 0, 0, 0);   // SWAPPED -> D[wo][n]
        }

        // LDS write: row = cl (n), logical byte = wo_local*4 = j*64 + rg*4,
        // stored at physical (logical ^ (cl&7)<<4). Uniform 8 accesses/bank.
#pragma unroll
        for (int j = 0; j < 16; ++j) {
            int byte = ((j << 6) + (rg << 2)) ^ ((cl & 7) << 4);
            *(f32x4*)(ldsw + (cl << 10) + byte) = acc[j];
        }

        // Readback row r: lane reads PHYSICAL chunk lane^(r&7), which holds
        // LOGICAL chunk lane -> store at logical float offset 4*lane. The
        // wave's 64x16B form one contiguous 1 KiB output span.
        const size_t row0 = (size_t)(n0 + wh * 16) * N_WO + it * 1024 + wq * 256;
#pragma unroll
        for (int r = 0; r < 16; ++r) {
            int phys = (lane << 4) ^ ((r & 7) << 4);
            f32x4 v = *(const f32x4*)(ldsw + (r << 10) + phys);
            v.x += bv.x; v.y += bv.y; v.z += bv.z; v.w += bv.w;
            *(f32x4*)(out + row0 + (size_t)r * N_WO + (lane << 2)) = v;
        }
    }
}

// Correctness fallback if d_ws is too small for the transposed panels.
__global__ __launch_bounds__(256) void naive_kernel(const float* __restrict__ x,
                                                    const float* __restrict__ wgt,
                                                    const float* __restrict__ bias,
                                                    float* __restrict__ out) {
    size_t idx = (size_t)blockIdx.x * 256 + threadIdx.x;
    if (idx >= OUT_TOTAL) return;
    int n    = (int)(idx >> 13);
    int ncol = (int)(idx & 8191);
    float s = 0.f;
    for (int i = 0; i < K_DIM; ++i)
        s += x[(size_t)i * N_X + n] * wgt[(size_t)i * N_WO + ncol];
    out[idx] = s + 128.0f * bias[ncol & 127];
}

extern "C" void kernel_launch(void* const* d_in, const int* in_sizes, int n_in,
                              void* d_out, int out_size, void* d_ws, size_t ws_size,
                              hipStream_t stream) {
    const float* x    = (const float*)d_in[0];   // [128][8192]
    const float* wgt  = (const float*)d_in[1];   // [128][64*128]
    const float* bias = (const float*)d_in[2];   // [128]
    float* out = (float*)d_out;

    if (ws_size >= 4u * 1024u * 1024u) {
        uint4* wsA = (uint4*)d_ws;                    // 2 MiB: x^T frag bf16
        uint4* wsB = wsA + CHUNKS_PER_PANEL;          // 2 MiB: W   frag bf16
        prep_frag2<<<1024, 256, 0, stream>>>(x, wgt, wsA);
        gemm_sweep2<<<256, 512, 131072, stream>>>((const short8*)wsA,
                                                  (const short8*)wsB, bias, out);
    } else {
        naive_kernel<<<(unsigned)((OUT_TOTAL + 255) / 256), 256, 0, stream>>>(
            x, wgt, bias, out);
    }
}

// Round 8
// 68.235 us; speedup vs baseline: 1.3896x; 1.3896x over previous
//
#include <hip/hip_runtime.h>
#include <hip/hip_bf16.h>
#include <stdint.h>

#define K_DIM 128
#define N_X   8192      // columns of x (the "n" / M dimension)
#define N_WO  8192      // 64*128 flattened (w,o) -> GEMM N dimension
#define OUT_TOTAL (8192UL * 64UL * 128UL)
#define CHUNKS_PER_PANEL 131072   // (8192/16 tiles) * 4 ksteps * 64 lanes

typedef __attribute__((ext_vector_type(8))) short short8;   // 8 bf16 = 4 VGPR
typedef __attribute__((ext_vector_type(4))) float f32x4;

__device__ inline unsigned short f2bf(float f) {
    union { float f; unsigned u; } v; v.f = f;
    unsigned u = v.u;
    u += 0x7fffu + ((u >> 16) & 1u);   // round-to-nearest-even
    return (unsigned short)(u >> 16);
}

// Transpose+convert BOTH panels P[128][8192] f32 (k-major, inner contiguous)
// into MFMA fragment-linear bf16 blocks. Chunk cc = ((t*4 + ks)*64 + l):
//   elem j (0..7): P[ks*32 + (l>>4)*8 + j][t*16 + (l&15)]
__global__ __launch_bounds__(256) void prep_frag2(const float* __restrict__ X,
                                                  const float* __restrict__ W,
                                                  uint4* __restrict__ Q) {
    int c  = blockIdx.x * 256 + threadIdx.x;   // 0 .. 262143
    int cc = c & (CHUNKS_PER_PANEL - 1);
    const float* P = (c >= CHUNKS_PER_PANEL) ? W : X;
    int l  = cc & 63;
    int ks = (cc >> 6) & 3;
    int t  = cc >> 8;
    int m  = t * 16 + (l & 15);
    int k0 = ks * 32 + ((l >> 4) << 3);
    const float* p = P + (size_t)k0 * N_X + m;
    unsigned short h[8];
#pragma unroll
    for (int j = 0; j < 8; ++j) h[j] = f2bf(p[(size_t)j * N_X]);
    uint4 q;
    q.x = (unsigned)h[0] | ((unsigned)h[1] << 16);
    q.y = (unsigned)h[2] | ((unsigned)h[3] << 16);
    q.z = (unsigned)h[4] | ((unsigned)h[5] << 16);
    q.w = (unsigned)h[6] | ((unsigned)h[7] << 16);
    Q[c] = q;
}

// Row-slab sweep GEMM, high-occupancy variant.
// Block = 32 output rows (n) x ALL 8192 wo, 1024 threads = 16 waves.
// Wave = 32n x 512 wo: 16 iterations of 2 wo-tiles x 2 n-tiles.
// Each W-tile is read by exactly one wave -> 2 MiB B-reads/block (amortized),
// 512 MiB total, L2-resident. No LDS, no barriers: stores flow continuously.
// VGPR kept under 128 (wf per-ks, bias from L1) -> 4 waves/SIMD at 1 blk/CU,
// 2x the latency hiding of the previous 512-thread variant.
// Operand-SWAPPED mfma: acc = mfma(Wfrag, xfrag) => D[wo][n]; each lane holds
// 4 consecutive wo at one n -> contiguous dwordx4 stores.
__global__ __launch_bounds__(1024, 4) void gemm_sweep3(const short8* __restrict__ A,
                                                       const short8* __restrict__ B,
                                                       const float* __restrict__ bias,
                                                       float* __restrict__ out) {
    int bid = blockIdx.x;
    // bijective XCD swizzle (256 % 8 == 0): 32 consecutive slabs per XCD
    int swz = (bid & 7) * 32 + (bid >> 3);
    int n0  = swz * 32;

    int tid  = threadIdx.x;
    int lane = tid & 63;
    int w    = tid >> 6;               // 0..15, owns wo [w*512, w*512+512)
    int cl = lane & 15, rg = (lane >> 4) << 2;

    // x fragments for this block's 2 row-tiles, all 4 K-steps (VGPR-resident)
    short8 xf[2][4];
#pragma unroll
    for (int i = 0; i < 2; ++i)
#pragma unroll
        for (int ks = 0; ks < 4; ++ks)
            xf[i][ks] = A[(size_t)((swz * 2 + i) * 4 + ks) * 64 + lane];

    // each lane stores into two fixed output rows for the whole kernel
    float* orow0 = out + (size_t)(n0 + cl) * N_WO;
    float* orow1 = orow0 + 16 * N_WO;

    int tw0 = w * 32;                  // wave's first wo-tile (512 wo = 32 tiles)

    for (int it = 0; it < 16; ++it) {
        int t0 = tw0 + it * 2;         // 2 wo-tiles this iteration
        f32x4 acc[2][2] = {};
#pragma unroll
        for (int ks = 0; ks < 4; ++ks) {
            short8 wf[2];
#pragma unroll
            for (int j = 0; j < 2; ++j)
                wf[j] = B[(size_t)((t0 + j) * 4 + ks) * 64 + lane];
#pragma unroll
            for (int i = 0; i < 2; ++i)
#pragma unroll
                for (int j = 0; j < 2; ++j)
                    acc[i][j] = __builtin_amdgcn_mfma_f32_16x16x32_bf16(
                        wf[j], xf[i][ks], acc[i][j], 0, 0, 0);  // D[wo][n]
        }

        // stores: col(lane&15)=n within tile i, row((lane>>4)*4+reg)=wo
#pragma unroll
        for (int j = 0; j < 2; ++j) {
            int wo = (t0 + j) * 16 + rg;
            const f32x4 bv = *(const f32x4*)(bias + (wo & 127));
            f32x4 v0 = acc[0][j], v1 = acc[1][j];
            v0.x += 128.0f * bv.x; v0.y += 128.0f * bv.y;
            v0.z += 128.0f * bv.z; v0.w += 128.0f * bv.w;
            v1.x += 128.0f * bv.x; v1.y += 128.0f * bv.y;
            v1.z += 128.0f * bv.z; v1.w += 128.0f * bv.w;
            *(f32x4*)(orow0 + wo) = v0;
            *(f32x4*)(orow1 + wo) = v1;
        }
    }
}

// Correctness fallback if d_ws is too small for the transposed panels.
__global__ __launch_bounds__(256) void naive_kernel(const float* __restrict__ x,
                                                    const float* __restrict__ wgt,
                                                    const float* __restrict__ bias,
                                                    float* __restrict__ out) {
    size_t idx = (size_t)blockIdx.x * 256 + threadIdx.x;
    if (idx >= OUT_TOTAL) return;
    int n    = (int)(idx >> 13);
    int ncol = (int)(idx & 8191);
    float s = 0.f;
    for (int i = 0; i < K_DIM; ++i)
        s += x[(size_t)i * N_X + n] * wgt[(size_t)i * N_WO + ncol];
    out[idx] = s + 128.0f * bias[ncol & 127];
}

extern "C" void kernel_launch(void* const* d_in, const int* in_sizes, int n_in,
                              void* d_out, int out_size, void* d_ws, size_t ws_size,
                              hipStream_t stream) {
    const float* x    = (const float*)d_in[0];   // [128][8192]
    const float* wgt  = (const float*)d_in[1];   // [128][64*128]
    const float* bias = (const float*)d_in[2];   // [128]
    float* out = (float*)d_out;

    if (ws_size >= 4u * 1024u * 1024u) {
        uint4* wsA = (uint4*)d_ws;                    // 2 MiB: x^T frag bf16
        uint4* wsB = wsA + CHUNKS_PER_PANEL;          // 2 MiB: W   frag bf16
        prep_frag2<<<1024, 256, 0, stream>>>(x, wgt, wsA);
        gemm_sweep3<<<256, 1024, 0, stream>>>((const short8*)wsA,
                                              (const short8*)wsB, bias, out);
    } else {
        naive_kernel<<<(unsigned)((OUT_TOTAL + 255) / 256), 256, 0, stream>>>(
            x, wgt, bias, out);
    }
}